// Round 12
// baseline (162.149 us; speedup 1.0000x reference)
//
#include <hip/hip_runtime.h>
#include <hip/hip_bf16.h>

// Problem constants
#define CIN   256
#define COUT  128
#define BATCH 16
#define HH    32
#define WW    32
#define KS    256       // silu K block (k = c)
#define KB    2048      // bases K block (k = c*8 + g)
#define M_TOT 16384     // BATCH*HH*WW
#define N_TOT 512       // COUT*2*2

typedef __bf16 bf16x8 __attribute__((ext_vector_type(8)));
typedef float  f32x4  __attribute__((ext_vector_type(4)));

// Literal Cox-de-Boor (tiny zbias path only). Knots g[i]=(i-3)*0.4-1.
__device__ __forceinline__ void bases8_ref(float v, float* bb) {
    float g[12];
#pragma unroll
    for (int i = 0; i < 12; ++i) g[i] = (float)(i - 3) * 0.4f - 1.0f;
    float b[11];
#pragma unroll
    for (int j = 0; j < 11; ++j) b[j] = (v >= g[j] && v < g[j + 1]) ? 1.0f : 0.0f;
#pragma unroll
    for (int k = 1; k <= 3; ++k) {
#pragma unroll
        for (int j = 0; j + k < 11; ++j) {
            float left  = (v - g[j]) / (g[j + k] - g[j]) * b[j];
            float right = (g[j + k + 1] - v) / (g[j + k + 1] - g[j + 1]) * b[j + 1];
            b[j] = left + right;
        }
    }
#pragma unroll
    for (int j = 0; j < 8; ++j) bb[j] = b[j];
}

// Kernel 1 (v5): coalesced x reads; features packed IN REGISTERS; per element
// exactly one bf16x8 (16B) store for the 8 bases + one 2B store for silu.
// Grid 1024 = (bh, w-half). LDS only for the x transpose (17 KB).
#define XS_LD 17
__global__ __launch_bounds__(256) void feat_kernel(const float* __restrict__ x,
                                                   __hip_bfloat16* __restrict__ As,
                                                   __hip_bfloat16* __restrict__ Ab) {
    __shared__ __align__(16) float xs[256 * XS_LD];        // 17408 B
    int bh = blockIdx.x >> 1;       // 0..511
    int wh = blockIdx.x & 1;        // 0..1
    int b = bh >> 5, h = bh & 31;
    int t = threadIdx.x;
    int w0 = wh * 16;

    // Phase A: coalesced x load; wave covers 16 rows x 64B.
    int ru = t >> 2, uu = t & 3;
#pragma unroll
    for (int pass = 0; pass < 4; ++pass) {
        int r = pass * 64 + ru;
        f32x4 v = *(const f32x4*)(x + (((size_t)(b * CIN + r) * HH + h) * WW) + w0 + uu * 4);
        *(f32x4*)&xs[r * XS_LD + uu * 4] = v;
    }
    __syncthreads();

    // Phase B: thread = channel c; 16 w's; register-packed stores.
    int c = t;
    size_t rowbase = (size_t)bh * 32 + w0;
#pragma unroll
    for (int w = 0; w < 16; ++w) {
        float v = xs[c * XS_LD + w];
        float s = v / (1.0f + __expf(-v));   // silu
        float u = v * 2.5f + 5.5f;           // (v + 2.2) / 0.4
        bool inr = (u >= 0.0f) && (u < 11.0f);
        float fidx = floorf(u);
        int idx = (int)fidx;
        float tt = u - fidx;
        float t2 = tt * tt, t3 = t2 * tt, omt = 1.0f - tt;
        float B0 = omt * omt * omt * (1.0f / 6.0f);
        float B1 = (3.0f * t3 - 6.0f * t2 + 4.0f) * (1.0f / 6.0f);
        float B2 = (-3.0f * t3 + 3.0f * t2 + 3.0f * tt + 1.0f) * (1.0f / 6.0f);
        float B3 = t3 * (1.0f / 6.0f);
        bf16x8 pk;
#pragma unroll
        for (int j = 0; j < 8; ++j) {
            int r_ = j - idx + 3;            // compile-time j, uniform idx
            float wv = (r_ == 0) ? B0 : (r_ == 1) ? B1 : (r_ == 2) ? B2 : (r_ == 3) ? B3 : 0.0f;
            pk[j] = (__bf16)(inr ? wv : 0.0f);
        }
        *(bf16x8*)(Ab + (rowbase + w) * KB + c * 8) = pk;
        As[(rowbase + w) * KS + c] = __float2bfloat16(s);
    }
}

// Kernel 2 (v3): blocks 0..511: one block per n, vectorized repack.
//                blocks 512..639: Z bias (direct global reads).
__global__ __launch_bounds__(256) void prep_kernel(const float* __restrict__ bw,
                                                   const float* __restrict__ sw,
                                                   __hip_bfloat16* __restrict__ Bs,
                                                   __hip_bfloat16* __restrict__ Bb,
                                                   float* __restrict__ Z) {
    if (blockIdx.x < 512) {
        int n = blockIdx.x;                 // n = o*4 + m2*2 + n2 (output tap)
        int o = n >> 2, mnp = n & 3;
        int src = 3 - mnp;                  // flipped source tap mf*2+nf
        int c = threadIdx.x;
        const float* wp = sw + (((size_t)(o * CIN + c) * 4 + src) * 8);
        f32x4 v0 = *(const f32x4*)wp;
        f32x4 v1 = *(const f32x4*)(wp + 4);
        bf16x8 pk;
#pragma unroll
        for (int i = 0; i < 4; ++i) { pk[i] = (__bf16)v0[i]; pk[4 + i] = (__bf16)v1[i]; }
        *(bf16x8*)(Bb + (size_t)n * KB + c * 8) = pk;
        float bv = bw[((size_t)(o * CIN + c) * 2 + (src >> 1)) * 2 + (src & 1)];
        Bs[(size_t)n * KS + c] = __float2bfloat16(bv);
    } else {
        int o = blockIdx.x - 512;           // 0..127
        int mn = threadIdx.x >> 6;          // 0..3 (storage order m*2+n)
        int lane = threadIdx.x & 63;
        float b0[8];
        bases8_ref(0.0f, b0);
        float p = 0.f;
        for (int cc = lane; cc < CIN; cc += 64) {
            const float* wp = sw + (((size_t)(o * CIN + cc) * 4 + mn) * 8);
#pragma unroll
            for (int gi = 0; gi < 8; ++gi) p += wp[gi] * b0[gi];
        }
#pragma unroll
        for (int off = 32; off; off >>= 1) p += __shfl_down(p, off);
        __shared__ float a4[4];
        if (lane == 0) a4[mn] = p;
        __syncthreads();
        if (threadIdx.x < 4) {
            float tot = a4[0] + a4[1] + a4[2] + a4[3];
            Z[o * 4 + (int)threadIdx.x] = tot - a4[3 - (int)threadIdx.x];
        }
    }
}

#define GLOBAL_AS __attribute__((address_space(1)))
#define LDS_AS    __attribute__((address_space(3)))
__device__ __forceinline__ void async_copy16(const void* g, void* l) {
    __builtin_amdgcn_global_load_lds((const GLOBAL_AS unsigned int*)g,
                                     (LDS_AS unsigned int*)l, 16, 0, 0);
}

// Kernel 3: GEMM over split-K: kt 0..3 -> silu block (stride 256),
// kt 4..35 -> bases block (stride 2048). Schedule unchanged from r8
// (2-phase dbuf + T2 XOR swizzle [conflicts=0] + T5 setprio).
__global__ __launch_bounds__(256) void gemm_kernel(const __hip_bfloat16* __restrict__ As,
                                                   const __hip_bfloat16* __restrict__ Ab,
                                                   const __hip_bfloat16* __restrict__ Bs,
                                                   const __hip_bfloat16* __restrict__ Bb,
                                                   const float* __restrict__ Z,
                                                   float* __restrict__ out) {
    __shared__ __align__(16) __hip_bfloat16 As0[128 * 64], Bs0[128 * 64];
    __shared__ __align__(16) __hip_bfloat16 As1[128 * 64], Bs1[128 * 64];
    int tid = threadIdx.x;
    int mBase = blockIdx.x * 128;
    int nBase = blockIdx.y * 128;
    int wave = tid >> 6, lane = tid & 63;
    int wm = wave >> 1, wn = wave & 1;
    int lrow = lane & 15, ksel = lane >> 4;
    int row_a = tid >> 3, oct = tid & 7;
    int soct = oct ^ (row_a & 7);          // pre-swizzled source 16B-unit

    f32x4 acc[4][4];
#pragma unroll
    for (int i = 0; i < 4; ++i)
#pragma unroll
        for (int j = 0; j < 4; ++j) acc[i][j] = (f32x4){0.f, 0.f, 0.f, 0.f};

    auto stage = [&](int kt, __hip_bfloat16* as, __hip_bfloat16* bs) {
        const __hip_bfloat16* ga0;
        const __hip_bfloat16* gb0;
        size_t strd;
        int k0;
        if (kt < 4) { k0 = kt * 64;        ga0 = As; gb0 = Bs; strd = KS; }
        else        { k0 = (kt - 4) * 64;  ga0 = Ab; gb0 = Bb; strd = KB; }
#pragma unroll
        for (int call = 0; call < 4; ++call) {
            int row = call * 32 + row_a;
            const __hip_bfloat16* ga = ga0 + (size_t)(mBase + row) * strd + k0 + soct * 8;
            const __hip_bfloat16* gb = gb0 + (size_t)(nBase + row) * strd + k0 + soct * 8;
            async_copy16(ga, as + (call * 256 + tid) * 8);
            async_copy16(gb, bs + (call * 256 + tid) * 8);
        }
    };
    auto compute = [&](const __hip_bfloat16* as, const __hip_bfloat16* bs) {
#pragma unroll
        for (int ks = 0; ks < 2; ++ks) {
            bf16x8 af[4], bfr[4];
#pragma unroll
            for (int f = 0; f < 4; ++f) {
                int ra = wm * 64 + f * 16 + lrow;
                int ua = (ks * 4 + ksel) ^ (ra & 7);
                af[f] = *(const bf16x8*)&as[ra * 64 + ua * 8];
                int rb = wn * 64 + f * 16 + lrow;
                int ub = (ks * 4 + ksel) ^ (rb & 7);
                bfr[f] = *(const bf16x8*)&bs[rb * 64 + ub * 8];
            }
            __builtin_amdgcn_s_setprio(1);
#pragma unroll
            for (int fm = 0; fm < 4; ++fm)
#pragma unroll
                for (int fn = 0; fn < 4; ++fn)
                    acc[fm][fn] = __builtin_amdgcn_mfma_f32_16x16x32_bf16(af[fm], bfr[fn], acc[fm][fn], 0, 0, 0);
            __builtin_amdgcn_s_setprio(0);
        }
    };

    stage(0, As0, Bs0);
    __syncthreads();
    for (int kt = 0; kt < 36; kt += 2) {
        stage(kt + 1, As1, Bs1);
        compute(As0, Bs0);
        __syncthreads();
        if (kt + 2 < 36) stage(kt + 2, As0, Bs0);
        compute(As1, Bs1);
        __syncthreads();
    }

    // Epilogue: C/D layout col = lane&15 (N), row = (lane>>4)*4 + reg (M) [m89].
#pragma unroll
    for (int fn = 0; fn < 4; ++fn) {
        int gn = nBase + wn * 64 + fn * 16 + lrow;
        float zv = Z[gn];
        int o = gn >> 2, m2 = (gn >> 1) & 1, n2 = gn & 1;
#pragma unroll
        for (int fm = 0; fm < 4; ++fm) {
#pragma unroll
            for (int r = 0; r < 4; ++r) {
                int gr = mBase + wm * 64 + fm * 16 + ksel * 4 + r;
                int b = gr >> 10, h = (gr >> 5) & 31, w = gr & 31;
                out[(((size_t)(b * COUT + o)) * 64 + (2 * h + m2)) * 64 + (2 * w + n2)] =
                    acc[fm][fn][r] + zv;
            }
        }
    }
}

extern "C" void kernel_launch(void* const* d_in, const int* in_sizes, int n_in,
                              void* d_out, int out_size, void* d_ws, size_t ws_size,
                              hipStream_t stream) {
    const float* x  = (const float*)d_in[0];
    const float* bw = (const float*)d_in[1];
    const float* sw = (const float*)d_in[2];
    float* out = (float*)d_out;

    __hip_bfloat16* A_silu  = (__hip_bfloat16*)d_ws;                     // 16384*256*2  = 8.39 MB
    __hip_bfloat16* A_bases = A_silu  + (size_t)M_TOT * KS;              // 16384*2048*2 = 67.1 MB
    __hip_bfloat16* B_silu  = A_bases + (size_t)M_TOT * KB;              // 512*256*2
    __hip_bfloat16* B_bases = B_silu  + (size_t)N_TOT * KS;              // 512*2048*2
    float*          Z       = (float*)(B_bases + (size_t)N_TOT * KB);    // 512*4 B

    feat_kernel<<<dim3(1024), dim3(256), 0, stream>>>(x, A_silu, A_bases);
    prep_kernel<<<dim3(640), dim3(256), 0, stream>>>(bw, sw, B_silu, B_bases, Z);
    gemm_kernel<<<dim3(128, 4), dim3(256), 0, stream>>>(A_silu, A_bases, B_silu, B_bases, Z, out);
}

// Round 13
// 158.102 us; speedup vs baseline: 1.0256x; 1.0256x over previous
//
#include <hip/hip_runtime.h>
#include <hip/hip_bf16.h>

// Problem constants
#define CIN   256
#define COUT  128
#define BATCH 16
#define HH    32
#define WW    32
#define KS    256       // silu K block (k = c)
#define KB    2048      // bases K block (k = c*8 + g)
#define M_TOT 16384     // BATCH*HH*WW
#define N_TOT 512       // COUT*2*2

typedef __bf16 bf16x8 __attribute__((ext_vector_type(8)));
typedef float  f32x4  __attribute__((ext_vector_type(4)));

// Literal Cox-de-Boor (tiny zbias path only). Knots g[i]=(i-3)*0.4-1.
__device__ __forceinline__ void bases8_ref(float v, float* bb) {
    float g[12];
#pragma unroll
    for (int i = 0; i < 12; ++i) g[i] = (float)(i - 3) * 0.4f - 1.0f;
    float b[11];
#pragma unroll
    for (int j = 0; j < 11; ++j) b[j] = (v >= g[j] && v < g[j + 1]) ? 1.0f : 0.0f;
#pragma unroll
    for (int k = 1; k <= 3; ++k) {
#pragma unroll
        for (int j = 0; j + k < 11; ++j) {
            float left  = (v - g[j]) / (g[j + k] - g[j]) * b[j];
            float right = (g[j + k + 1] - v) / (g[j + k + 1] - g[j + 1]) * b[j + 1];
            b[j] = left + right;
        }
    }
#pragma unroll
    for (int j = 0; j < 8; ++j) bb[j] = b[j];
}

// Kernel 1 (v5, UNCHANGED from r12): coalesced x reads; register-packed
// features; one bf16x8 + one 2B store per element.
#define XS_LD 17
__global__ __launch_bounds__(256) void feat_kernel(const float* __restrict__ x,
                                                   __hip_bfloat16* __restrict__ As,
                                                   __hip_bfloat16* __restrict__ Ab) {
    __shared__ __align__(16) float xs[256 * XS_LD];        // 17408 B
    int bh = blockIdx.x >> 1;       // 0..511
    int wh = blockIdx.x & 1;        // 0..1
    int b = bh >> 5, h = bh & 31;
    int t = threadIdx.x;
    int w0 = wh * 16;

    int ru = t >> 2, uu = t & 3;
#pragma unroll
    for (int pass = 0; pass < 4; ++pass) {
        int r = pass * 64 + ru;
        f32x4 v = *(const f32x4*)(x + (((size_t)(b * CIN + r) * HH + h) * WW) + w0 + uu * 4);
        *(f32x4*)&xs[r * XS_LD + uu * 4] = v;
    }
    __syncthreads();

    int c = t;
    size_t rowbase = (size_t)bh * 32 + w0;
#pragma unroll
    for (int w = 0; w < 16; ++w) {
        float v = xs[c * XS_LD + w];
        float s = v / (1.0f + __expf(-v));   // silu
        float u = v * 2.5f + 5.5f;           // (v + 2.2) / 0.4
        bool inr = (u >= 0.0f) && (u < 11.0f);
        float fidx = floorf(u);
        int idx = (int)fidx;
        float tt = u - fidx;
        float t2 = tt * tt, t3 = t2 * tt, omt = 1.0f - tt;
        float B0 = omt * omt * omt * (1.0f / 6.0f);
        float B1 = (3.0f * t3 - 6.0f * t2 + 4.0f) * (1.0f / 6.0f);
        float B2 = (-3.0f * t3 + 3.0f * t2 + 3.0f * tt + 1.0f) * (1.0f / 6.0f);
        float B3 = t3 * (1.0f / 6.0f);
        bf16x8 pk;
#pragma unroll
        for (int j = 0; j < 8; ++j) {
            int r_ = j - idx + 3;
            float wv = (r_ == 0) ? B0 : (r_ == 1) ? B1 : (r_ == 2) ? B2 : (r_ == 3) ? B3 : 0.0f;
            pk[j] = (__bf16)(inr ? wv : 0.0f);
        }
        *(bf16x8*)(Ab + (rowbase + w) * KB + c * 8) = pk;
        As[(rowbase + w) * KS + c] = __float2bfloat16(s);
    }
}

// Kernel 2 (v4): blocks 0..511 repack (unchanged, provably tiny);
// blocks 512..639 zbias with COALESCED LDS-staged reads (fixes r12's
// latency-bound 128B-stride gather at 0.5 blocks/CU).
__global__ __launch_bounds__(256) void prep_kernel(const float* __restrict__ bw,
                                                   const float* __restrict__ sw,
                                                   __hip_bfloat16* __restrict__ Bs,
                                                   __hip_bfloat16* __restrict__ Bb,
                                                   float* __restrict__ Z) {
    if (blockIdx.x < 512) {
        int n = blockIdx.x;                 // n = o*4 + m2*2 + n2 (output tap)
        int o = n >> 2, mnp = n & 3;
        int src = 3 - mnp;                  // flipped source tap mf*2+nf
        int c = threadIdx.x;
        const float* wp = sw + (((size_t)(o * CIN + c) * 4 + src) * 8);
        f32x4 v0 = *(const f32x4*)wp;
        f32x4 v1 = *(const f32x4*)(wp + 4);
        bf16x8 pk;
#pragma unroll
        for (int i = 0; i < 4; ++i) { pk[i] = (__bf16)v0[i]; pk[4 + i] = (__bf16)v1[i]; }
        *(bf16x8*)(Bb + (size_t)n * KB + c * 8) = pk;
        float bv = bw[((size_t)(o * CIN + c) * 2 + (src >> 1)) * 2 + (src & 1)];
        Bs[(size_t)n * KS + c] = __float2bfloat16(bv);
    } else {
        __shared__ float ls[256 * 33];      // 33792 B, [c][mn*8+g] pad-33
        __shared__ float wa[4][4];
        __shared__ float a4[4];
        int o = blockIdx.x - 512;           // 0..127
        int t = threadIdx.x;
        const float* sp = sw + (size_t)o * (CIN * 32);
        // Coalesced linear load: 2048 float4s, 8 per thread.
#pragma unroll
        for (int pass = 0; pass < 8; ++pass) {
            int f = (pass * 256 + t) * 4;
            f32x4 v = *(const f32x4*)(sp + f);
#pragma unroll
            for (int i = 0; i < 4; ++i) {
                int fi = f + i;
                ls[(fi >> 5) * 33 + (fi & 31)] = v[i];
            }
        }
        __syncthreads();
        float b0[8];
        bases8_ref(0.0f, b0);
        // Thread t = channel c: partial dot per mn. Banks (t*33+k)%32 = (t+k)%32.
        float p[4] = {0.f, 0.f, 0.f, 0.f};
#pragma unroll
        for (int mn = 0; mn < 4; ++mn)
#pragma unroll
            for (int gi = 0; gi < 8; ++gi)
                p[mn] += ls[t * 33 + mn * 8 + gi] * b0[gi];
        int lane = t & 63, wv = t >> 6;
#pragma unroll
        for (int off = 32; off; off >>= 1)
#pragma unroll
            for (int mn = 0; mn < 4; ++mn) p[mn] += __shfl_down(p[mn], off);
        if (lane == 0) {
#pragma unroll
            for (int mn = 0; mn < 4; ++mn) wa[wv][mn] = p[mn];
        }
        __syncthreads();
        if (t < 4) a4[t] = wa[0][t] + wa[1][t] + wa[2][t] + wa[3][t];
        __syncthreads();
        if (t < 4) {
            float tot = a4[0] + a4[1] + a4[2] + a4[3];
            Z[o * 4 + t] = tot - a4[3 - t];
        }
    }
}

#define GLOBAL_AS __attribute__((address_space(1)))
#define LDS_AS    __attribute__((address_space(3)))
__device__ __forceinline__ void async_copy16(const void* g, void* l) {
    __builtin_amdgcn_global_load_lds((const GLOBAL_AS unsigned int*)g,
                                     (LDS_AS unsigned int*)l, 16, 0, 0);
}

// Kernel 3 (UNCHANGED from r12): split-K GEMM, 2ph dbuf + T2 swizzle + T5.
__global__ __launch_bounds__(256) void gemm_kernel(const __hip_bfloat16* __restrict__ As,
                                                   const __hip_bfloat16* __restrict__ Ab,
                                                   const __hip_bfloat16* __restrict__ Bs,
                                                   const __hip_bfloat16* __restrict__ Bb,
                                                   const float* __restrict__ Z,
                                                   float* __restrict__ out) {
    __shared__ __align__(16) __hip_bfloat16 As0[128 * 64], Bs0[128 * 64];
    __shared__ __align__(16) __hip_bfloat16 As1[128 * 64], Bs1[128 * 64];
    int tid = threadIdx.x;
    int mBase = blockIdx.x * 128;
    int nBase = blockIdx.y * 128;
    int wave = tid >> 6, lane = tid & 63;
    int wm = wave >> 1, wn = wave & 1;
    int lrow = lane & 15, ksel = lane >> 4;
    int row_a = tid >> 3, oct = tid & 7;
    int soct = oct ^ (row_a & 7);          // pre-swizzled source 16B-unit

    f32x4 acc[4][4];
#pragma unroll
    for (int i = 0; i < 4; ++i)
#pragma unroll
        for (int j = 0; j < 4; ++j) acc[i][j] = (f32x4){0.f, 0.f, 0.f, 0.f};

    auto stage = [&](int kt, __hip_bfloat16* as, __hip_bfloat16* bs) {
        const __hip_bfloat16* ga0;
        const __hip_bfloat16* gb0;
        size_t strd;
        int k0;
        if (kt < 4) { k0 = kt * 64;        ga0 = As; gb0 = Bs; strd = KS; }
        else        { k0 = (kt - 4) * 64;  ga0 = Ab; gb0 = Bb; strd = KB; }
#pragma unroll
        for (int call = 0; call < 4; ++call) {
            int row = call * 32 + row_a;
            const __hip_bfloat16* ga = ga0 + (size_t)(mBase + row) * strd + k0 + soct * 8;
            const __hip_bfloat16* gb = gb0 + (size_t)(nBase + row) * strd + k0 + soct * 8;
            async_copy16(ga, as + (call * 256 + tid) * 8);
            async_copy16(gb, bs + (call * 256 + tid) * 8);
        }
    };
    auto compute = [&](const __hip_bfloat16* as, const __hip_bfloat16* bs) {
#pragma unroll
        for (int ks = 0; ks < 2; ++ks) {
            bf16x8 af[4], bfr[4];
#pragma unroll
            for (int f = 0; f < 4; ++f) {
                int ra = wm * 64 + f * 16 + lrow;
                int ua = (ks * 4 + ksel) ^ (ra & 7);
                af[f] = *(const bf16x8*)&as[ra * 64 + ua * 8];
                int rb = wn * 64 + f * 16 + lrow;
                int ub = (ks * 4 + ksel) ^ (rb & 7);
                bfr[f] = *(const bf16x8*)&bs[rb * 64 + ub * 8];
            }
            __builtin_amdgcn_s_setprio(1);
#pragma unroll
            for (int fm = 0; fm < 4; ++fm)
#pragma unroll
                for (int fn = 0; fn < 4; ++fn)
                    acc[fm][fn] = __builtin_amdgcn_mfma_f32_16x16x32_bf16(af[fm], bfr[fn], acc[fm][fn], 0, 0, 0);
            __builtin_amdgcn_s_setprio(0);
        }
    };

    stage(0, As0, Bs0);
    __syncthreads();
    for (int kt = 0; kt < 36; kt += 2) {
        stage(kt + 1, As1, Bs1);
        compute(As0, Bs0);
        __syncthreads();
        if (kt + 2 < 36) stage(kt + 2, As0, Bs0);
        compute(As1, Bs1);
        __syncthreads();
    }

    // Epilogue: C/D layout col = lane&15 (N), row = (lane>>4)*4 + reg (M) [m89].
#pragma unroll
    for (int fn = 0; fn < 4; ++fn) {
        int gn = nBase + wn * 64 + fn * 16 + lrow;
        float zv = Z[gn];
        int o = gn >> 2, m2 = (gn >> 1) & 1, n2 = gn & 1;
#pragma unroll
        for (int fm = 0; fm < 4; ++fm) {
#pragma unroll
            for (int r = 0; r < 4; ++r) {
                int gr = mBase + wm * 64 + fm * 16 + ksel * 4 + r;
                int b = gr >> 10, h = (gr >> 5) & 31, w = gr & 31;
                out[(((size_t)(b * COUT + o)) * 64 + (2 * h + m2)) * 64 + (2 * w + n2)] =
                    acc[fm][fn][r] + zv;
            }
        }
    }
}

extern "C" void kernel_launch(void* const* d_in, const int* in_sizes, int n_in,
                              void* d_out, int out_size, void* d_ws, size_t ws_size,
                              hipStream_t stream) {
    const float* x  = (const float*)d_in[0];
    const float* bw = (const float*)d_in[1];
    const float* sw = (const float*)d_in[2];
    float* out = (float*)d_out;

    __hip_bfloat16* A_silu  = (__hip_bfloat16*)d_ws;                     // 16384*256*2  = 8.39 MB
    __hip_bfloat16* A_bases = A_silu  + (size_t)M_TOT * KS;              // 16384*2048*2 = 67.1 MB
    __hip_bfloat16* B_silu  = A_bases + (size_t)M_TOT * KB;              // 512*256*2
    __hip_bfloat16* B_bases = B_silu  + (size_t)N_TOT * KS;              // 512*2048*2
    float*          Z       = (float*)(B_bases + (size_t)N_TOT * KB);    // 512*4 B

    feat_kernel<<<dim3(1024), dim3(256), 0, stream>>>(x, A_silu, A_bases);
    prep_kernel<<<dim3(640), dim3(256), 0, stream>>>(bw, sw, B_silu, B_bases, Z);
    gemm_kernel<<<dim3(128, 4), dim3(256), 0, stream>>>(A_silu, A_bases, B_silu, B_bases, Z, out);
}

// Round 14
// 144.908 us; speedup vs baseline: 1.1190x; 1.0911x over previous
//
#include <hip/hip_runtime.h>
#include <hip/hip_bf16.h>

// Problem constants
#define CIN   256
#define COUT  128
#define BATCH 16
#define HH    32
#define WW    32
#define KD    2304      // 9 * 256, k = j*256 + c (j=0: silu, j=1..8: bases)
#define M_TOT 16384     // BATCH*HH*WW
#define N_TOT 512       // COUT*2*2

typedef __bf16 bf16x8 __attribute__((ext_vector_type(8)));
typedef float  f32x4  __attribute__((ext_vector_type(4)));

// Literal Cox-de-Boor (tiny zbias path only). Knots g[i]=(i-3)*0.4-1.
__device__ __forceinline__ void bases8_ref(float v, float* bb) {
    float g[12];
#pragma unroll
    for (int i = 0; i < 12; ++i) g[i] = (float)(i - 3) * 0.4f - 1.0f;
    float b[11];
#pragma unroll
    for (int j = 0; j < 11; ++j) b[j] = (v >= g[j] && v < g[j + 1]) ? 1.0f : 0.0f;
#pragma unroll
    for (int k = 1; k <= 3; ++k) {
#pragma unroll
        for (int j = 0; j + k < 11; ++j) {
            float left  = (v - g[j]) / (g[j + k] - g[j]) * b[j];
            float right = (g[j + k + 1] - v) / (g[j + k + 1] - g[j + 1]) * b[j + 1];
            b[j] = left + right;
        }
    }
#pragma unroll
    for (int j = 0; j < 8; ++j) bb[j] = b[j];
}

// Kernel 1 (v4, EXACT r8 measured-best): coalesced x reads + LDS feature tile
// (indexed scatter) + bf16x8 coalesced flush. Interleaved A[row][j*256+c].
#define XS_LD 17
__global__ __launch_bounds__(256) void feat_kernel(const float* __restrict__ x,
                                                   __hip_bfloat16* __restrict__ A) {
    __shared__ __align__(16) float xs[256 * XS_LD];        // 17408 B
    __shared__ __align__(16) __hip_bfloat16 lf[4 * KD];    // 18432 B
    int bh = blockIdx.x >> 1;       // 0..511
    int wh = blockIdx.x & 1;        // 0..1
    int b = bh >> 5, h = bh & 31;
    int t = threadIdx.x;
    int w0 = wh * 16;

    // Phase A: coalesced x load; wave covers 16 rows x 64B.
    int ru = t >> 2, uu = t & 3;
#pragma unroll
    for (int pass = 0; pass < 4; ++pass) {
        int r = pass * 64 + ru;
        f32x4 v = *(const f32x4*)(x + (((size_t)(b * CIN + r) * HH + h) * WW) + w0 + uu * 4);
        *(f32x4*)&xs[r * XS_LD + uu * 4] = v;
    }
    __syncthreads();

    int c = t;
    size_t rowbase = (size_t)bh * 32 + w0;
    for (int chunk = 0; chunk < 4; ++chunk) {
        // Phase B: 4 w's -> lf. Scatter banks: bank = c>>1 (j*512B bank-neutral),
        // 2 lanes/bank = free (m136).
#pragma unroll
        for (int wi = 0; wi < 4; ++wi) {
            float v = xs[c * XS_LD + chunk * 4 + wi];
            float s = v / (1.0f + __expf(-v));   // silu
            float u = v * 2.5f + 5.5f;           // (v + 2.2) / 0.4
            bool inr = (u >= 0.0f) && (u < 11.0f);
            float fidx = floorf(u);
            int idx = (int)fidx;
            float tt = u - fidx;
            float t2 = tt * tt, t3 = t2 * tt, omt = 1.0f - tt;
            float B0 = omt * omt * omt * (1.0f / 6.0f);
            float B1 = (3.0f * t3 - 6.0f * t2 + 4.0f) * (1.0f / 6.0f);
            float B2 = (-3.0f * t3 + 3.0f * t2 + 3.0f * tt + 1.0f) * (1.0f / 6.0f);
            float B3 = t3 * (1.0f / 6.0f);
            float Bv[4] = {B0, B1, B2, B3};
            __hip_bfloat16* lp = lf + wi * KD + c;
            lp[0] = __float2bfloat16(s);
#pragma unroll
            for (int j = 1; j <= 8; ++j) lp[j * 256] = __float2bfloat16(0.0f);
            if (inr) {
#pragma unroll
                for (int r_ = 0; r_ < 4; ++r_) {
                    int j = idx - 3 + r_;
                    if ((unsigned)j < 8u) lp[(j + 1) * 256] = __float2bfloat16(Bv[r_]);
                }
            }
        }
        __syncthreads();
        // Phase C: flush 4 rows x 288 16B-units, fully coalesced.
        for (int sid = t; sid < 1152; sid += 256) {
            int row = sid / 288, off = sid - row * 288;
            bf16x8 vv = *(const bf16x8*)&lf[row * KD + off * 8];
            *(bf16x8*)(A + (rowbase + chunk * 4 + row) * KD + off * 8) = vv;
        }
        __syncthreads();
    }
}

// Kernel 2 (v6): blocks 0..511 direct repack -> interleaved Bm[n][j*256+c];
// blocks 512..639 zbias with coalesced LDS-staged reads (r13's fix).
__global__ __launch_bounds__(256) void prep_kernel(const float* __restrict__ bw,
                                                   const float* __restrict__ sw,
                                                   __hip_bfloat16* __restrict__ Bm,
                                                   float* __restrict__ Z) {
    if (blockIdx.x < 512) {
        int n = blockIdx.x;                 // n = o*4 + m2*2 + n2 (output tap)
        int o = n >> 2, mnp = n & 3;
        int src = 3 - mnp;                  // flipped source tap mf*2+nf
        int c = threadIdx.x;
        const float* wp = sw + (((size_t)(o * CIN + c) * 4 + src) * 8);
        f32x4 v0 = *(const f32x4*)wp;
        f32x4 v1 = *(const f32x4*)(wp + 4);
        float bv = bw[((size_t)(o * CIN + c) * 2 + (src >> 1)) * 2 + (src & 1)];
        __hip_bfloat16* bp = Bm + (size_t)n * KD + c;
        bp[0] = __float2bfloat16(bv);
#pragma unroll
        for (int i = 0; i < 4; ++i) {
            bp[(size_t)(1 + i) * 256] = __float2bfloat16(v0[i]);
            bp[(size_t)(5 + i) * 256] = __float2bfloat16(v1[i]);
        }
    } else {
        __shared__ float ls[256 * 33];      // 33792 B, [c][mn*8+g] pad-33
        __shared__ float wa[4][4];
        __shared__ float a4[4];
        int o = blockIdx.x - 512;           // 0..127
        int t = threadIdx.x;
        const float* sp = sw + (size_t)o * (CIN * 32);
#pragma unroll
        for (int pass = 0; pass < 8; ++pass) {
            int f = (pass * 256 + t) * 4;
            f32x4 v = *(const f32x4*)(sp + f);
#pragma unroll
            for (int i = 0; i < 4; ++i) {
                int fi = f + i;
                ls[(fi >> 5) * 33 + (fi & 31)] = v[i];
            }
        }
        __syncthreads();
        float b0[8];
        bases8_ref(0.0f, b0);
        float p[4] = {0.f, 0.f, 0.f, 0.f};
#pragma unroll
        for (int mn = 0; mn < 4; ++mn)
#pragma unroll
            for (int gi = 0; gi < 8; ++gi)
                p[mn] += ls[t * 33 + mn * 8 + gi] * b0[gi];
        int lane = t & 63, wv = t >> 6;
#pragma unroll
        for (int off = 32; off; off >>= 1)
#pragma unroll
            for (int mn = 0; mn < 4; ++mn) p[mn] += __shfl_down(p[mn], off);
        if (lane == 0) {
#pragma unroll
            for (int mn = 0; mn < 4; ++mn) wa[wv][mn] = p[mn];
        }
        __syncthreads();
        if (t < 4) a4[t] = wa[0][t] + wa[1][t] + wa[2][t] + wa[3][t];
        __syncthreads();
        if (t < 4) {
            float tot = a4[0] + a4[1] + a4[2] + a4[3];
            Z[o * 4 + t] = tot - a4[3 - t];
        }
    }
}

#define GLOBAL_AS __attribute__((address_space(1)))
#define LDS_AS    __attribute__((address_space(3)))
__device__ __forceinline__ void async_copy16(const void* g, void* l) {
    __builtin_amdgcn_global_load_lds((const GLOBAL_AS unsigned int*)g,
                                     (LDS_AS unsigned int*)l, 16, 0, 0);
}

// Kernel 3 (EXACT r8 measured 55.5us): interleaved-layout GEMM,
// 2ph dbuf + T2 XOR swizzle (conflicts=0) + T5 setprio.
__global__ __launch_bounds__(256) void gemm_kernel(const __hip_bfloat16* __restrict__ A,
                                                   const __hip_bfloat16* __restrict__ Bm,
                                                   const float* __restrict__ Z,
                                                   float* __restrict__ out) {
    __shared__ __align__(16) __hip_bfloat16 As0[128 * 64], Bs0[128 * 64];
    __shared__ __align__(16) __hip_bfloat16 As1[128 * 64], Bs1[128 * 64];
    int tid = threadIdx.x;
    int mBase = blockIdx.x * 128;
    int nBase = blockIdx.y * 128;
    int wave = tid >> 6, lane = tid & 63;
    int wm = wave >> 1, wn = wave & 1;
    int lrow = lane & 15, ksel = lane >> 4;
    int row_a = tid >> 3, oct = tid & 7;
    int soct = oct ^ (row_a & 7);          // pre-swizzled source 16B-unit

    f32x4 acc[4][4];
#pragma unroll
    for (int i = 0; i < 4; ++i)
#pragma unroll
        for (int j = 0; j < 4; ++j) acc[i][j] = (f32x4){0.f, 0.f, 0.f, 0.f};

    auto stage = [&](int kt, __hip_bfloat16* as, __hip_bfloat16* bs) {
        int k0 = kt * 64;
#pragma unroll
        for (int call = 0; call < 4; ++call) {
            int row = call * 32 + row_a;
            const __hip_bfloat16* ga = A  + (size_t)(mBase + row) * KD + k0 + soct * 8;
            const __hip_bfloat16* gb = Bm + (size_t)(nBase + row) * KD + k0 + soct * 8;
            async_copy16(ga, as + (call * 256 + tid) * 8);
            async_copy16(gb, bs + (call * 256 + tid) * 8);
        }
    };
    auto compute = [&](const __hip_bfloat16* as, const __hip_bfloat16* bs) {
#pragma unroll
        for (int ks = 0; ks < 2; ++ks) {
            bf16x8 af[4], bfr[4];
#pragma unroll
            for (int f = 0; f < 4; ++f) {
                int ra = wm * 64 + f * 16 + lrow;
                int ua = (ks * 4 + ksel) ^ (ra & 7);
                af[f] = *(const bf16x8*)&as[ra * 64 + ua * 8];
                int rb = wn * 64 + f * 16 + lrow;
                int ub = (ks * 4 + ksel) ^ (rb & 7);
                bfr[f] = *(const bf16x8*)&bs[rb * 64 + ub * 8];
            }
            __builtin_amdgcn_s_setprio(1);
#pragma unroll
            for (int fm = 0; fm < 4; ++fm)
#pragma unroll
                for (int fn = 0; fn < 4; ++fn)
                    acc[fm][fn] = __builtin_amdgcn_mfma_f32_16x16x32_bf16(af[fm], bfr[fn], acc[fm][fn], 0, 0, 0);
            __builtin_amdgcn_s_setprio(0);
        }
    };

    stage(0, As0, Bs0);
    __syncthreads();
    for (int kt = 0; kt < 36; kt += 2) {
        stage(kt + 1, As1, Bs1);
        compute(As0, Bs0);
        __syncthreads();
        if (kt + 2 < 36) stage(kt + 2, As0, Bs0);
        compute(As1, Bs1);
        __syncthreads();
    }

    // Epilogue: C/D layout col = lane&15 (N), row = (lane>>4)*4 + reg (M) [m89].
#pragma unroll
    for (int fn = 0; fn < 4; ++fn) {
        int gn = nBase + wn * 64 + fn * 16 + lrow;
        float zv = Z[gn];
        int o = gn >> 2, m2 = (gn >> 1) & 1, n2 = gn & 1;
#pragma unroll
        for (int fm = 0; fm < 4; ++fm) {
#pragma unroll
            for (int r = 0; r < 4; ++r) {
                int gr = mBase + wm * 64 + fm * 16 + ksel * 4 + r;
                int b = gr >> 10, h = (gr >> 5) & 31, w = gr & 31;
                out[(((size_t)(b * COUT + o)) * 64 + (2 * h + m2)) * 64 + (2 * w + n2)] =
                    acc[fm][fn][r] + zv;
            }
        }
    }
}

extern "C" void kernel_launch(void* const* d_in, const int* in_sizes, int n_in,
                              void* d_out, int out_size, void* d_ws, size_t ws_size,
                              hipStream_t stream) {
    const float* x  = (const float*)d_in[0];
    const float* bw = (const float*)d_in[1];
    const float* sw = (const float*)d_in[2];
    float* out = (float*)d_out;

    __hip_bfloat16* Afeat = (__hip_bfloat16*)d_ws;                       // 16384*2304*2 B
    __hip_bfloat16* Bm    = Afeat + (size_t)M_TOT * KD;                  // 512*2304*2 B
    float*          Z     = (float*)(Bm + (size_t)N_TOT * KD);           // 512*4 B

    feat_kernel<<<dim3(1024), dim3(256), 0, stream>>>(x, Afeat);
    prep_kernel<<<dim3(640), dim3(256), 0, stream>>>(bw, sw, Bm, Z);
    gemm_kernel<<<dim3(128, 4), dim3(256), 0, stream>>>(Afeat, Bm, Z, out);
}